// Round 2
// baseline (473.175 us; speedup 1.0000x reference)
//
#include <hip/hip_runtime.h>
#include <math.h>

// Problem constants: B=2, D_e=128, D_o=256, T=16, H=W=64, H_ref=W_ref=32, s=2, k=32
// n_blocks = T*H_ref*W_ref = 16384 per batch; HW_ref = 1024 query blocks per batch.

// ---------------- workspace layout (bytes) ----------------
// [0, 134217728)      : m_out_b [2][16384][4][256] f32 (written by blockify AFTER topk done)
//   -- transient (dead before m_out_b is written, stream-ordered):
//   [0, 4194304)        : cand [2][1024][256] u64 candidate keys
//   [4194304, 4718592)  : Mx [2][1024][64] f32 chunk maxima
//   [4718592, 4726784)  : t_u [2048] u32 per-column thresholds (mono space)
//   [4726784, 4734976)  : cnt [2048] i32 per-column candidate counts
// [134217728, +64MB)  : m_in_b [2][16384][4][128] f32
// [201326592, +4MB)   : q_b [2][1024][4][128] f32
// [205520896, +256KB) : idx_sorted [2][1024][32] int32

__device__ inline unsigned mono_u32(float f) {
    unsigned b = __float_as_uint(f);
    return (b & 0x80000000u) ? ~b : (b | 0x80000000u);
}

// ---------------- kernel A1: per-(column, 256-row chunk) maxima ----------------
// qk row-major [B,16384,1024]; thread owns one column, scans 256 rows (stride 4KB),
// 16-deep load staging for latency coverage. Reads fully coalesced (256B/wave/row).
__global__ __launch_bounds__(256) void qk_chunk_max(const float* __restrict__ qk,
                                                    float* __restrict__ Mx) {
    int wg = blockIdx.x;                 // b*256 + chunk*4 + cg
    int cg = wg & 3;
    int chunk = (wg >> 2) & 63;
    int b = wg >> 8;
    int col = cg * 256 + threadIdx.x;
    const float* p = qk + ((size_t)b * 16384 + (size_t)chunk * 256) * 1024 + col;
    float m = -__builtin_inff();
#pragma unroll
    for (int rb = 0; rb < 16; ++rb) {
        float vv[16];
#pragma unroll
        for (int u = 0; u < 16; ++u)
            vv[u] = p[(size_t)(rb * 16 + u) * 1024];
#pragma unroll
        for (int u = 0; u < 16; ++u) m = fmaxf(m, vv[u]);
    }
    Mx[((size_t)b * 1024 + col) * 64 + chunk] = m;
}

// ---------------- kernel A2: conservative per-column threshold ----------------
// t = 32nd-largest of the 64 chunk maxima (by distinct u64 key). >=32 chunks have
// max >= t  =>  >=32 elements >= t  =>  t <= true 32nd-largest element. Also zeroes cnt.
__global__ __launch_bounds__(256) void qk_thresh(const float* __restrict__ Mx,
                                                 unsigned* __restrict__ t_u,
                                                 int* __restrict__ cnt) {
    int g = blockIdx.x * 256 + threadIdx.x;
    if (g < 2048) cnt[g] = 0;
    int colg = blockIdx.x * 4 + (threadIdx.x >> 6);   // 0..2047 (grid 512 wgs)
    int lane = threadIdx.x & 63;
    float mv = Mx[(size_t)colg * 64 + lane];
    unsigned long long key = ((unsigned long long)mono_u32(mv) << 32) | (unsigned)lane;
    int rank = 0;
#pragma unroll 8
    for (int j = 0; j < 64; ++j) {
        unsigned long long other = __shfl(key, j, 64);
        rank += (other > key) ? 1 : 0;
    }
    if (rank == 31) t_u[colg] = (unsigned)(key >> 32);
}

// ---------------- kernel A3: filter pass — append candidates >= t ----------------
// Second coalesced stream of qk (likely L3-resident after A1). ~44 survivors/column.
__global__ __launch_bounds__(256) void qk_filter(const float* __restrict__ qk,
                                                 const unsigned* __restrict__ t_u,
                                                 int* __restrict__ cnt,
                                                 unsigned long long* __restrict__ cand) {
    int wg = blockIdx.x;
    int cg = wg & 3;
    int chunk = (wg >> 2) & 63;
    int b = wg >> 8;
    int col = cg * 256 + threadIdx.x;
    int colg = b * 1024 + col;
    unsigned t = t_u[colg];
    const float* p = qk + ((size_t)b * 16384 + (size_t)chunk * 256) * 1024 + col;
    int n0 = chunk * 256;
#pragma unroll
    for (int rb = 0; rb < 16; ++rb) {
        float vv[16];
#pragma unroll
        for (int u = 0; u < 16; ++u)
            vv[u] = p[(size_t)(rb * 16 + u) * 1024];
#pragma unroll
        for (int u = 0; u < 16; ++u) {
            unsigned uu = mono_u32(vv[u]);
            if (uu >= t) {
                int pos = atomicAdd(&cnt[colg], 1);
                if (pos < 256) {
                    int gi = n0 + rb * 16 + u;
                    cand[(size_t)colg * 256 + pos] =
                        ((unsigned long long)uu << 32) |
                        (unsigned long long)(16383 - gi);
                }
            }
        }
    }
}

// ---------------- kernel B: exact top-32 from candidates ----------------
// Rank-count over C (~44) u64 keys (val desc, idx asc on ties — jax order).
// C >= 32 guaranteed by threshold proof. C > 256 (never for this data): exact
// direct-scan fallback over the raw column.
__global__ __launch_bounds__(256) void topk_select(const unsigned long long* __restrict__ cand,
                                                   const int* __restrict__ cnt,
                                                   const float* __restrict__ qk,
                                                   float* __restrict__ out_idx,
                                                   float* __restrict__ out_val,
                                                   int* __restrict__ idx_sorted) {
    int bid = blockIdx.x;                // colg = b*1024 + q
    int tid = threadIdx.x;
    __shared__ unsigned long long sc[256];
    __shared__ unsigned long long selk[32];

    int C = cnt[bid];
    if (C <= 256) {
        if (tid < C) sc[tid] = cand[(size_t)bid * 256 + tid];
        __syncthreads();
        if (tid < C) {
            unsigned long long mine = sc[tid];
            int rank = 0;
            for (int j = 0; j < C; ++j) rank += (sc[j] > mine) ? 1 : 0;
            if (rank < 32) selk[rank] = mine;
        }
        __syncthreads();
    } else {
        // exact fallback: 32 rounds of strictly-descending key extraction
        int b = bid >> 10, q = bid & 1023;
        const float* colp = qk + (size_t)b * 16384 * 1024 + q;
        unsigned long long prev = ~0ull;
#pragma unroll 1
        for (int s = 0; s < 32; ++s) {
            unsigned long long best = 0;
            for (int r = tid; r < 16384; r += 256) {
                unsigned long long k =
                    ((unsigned long long)mono_u32(colp[(size_t)r * 1024]) << 32) |
                    (unsigned long long)(16383 - r);
                if (k < prev && k > best) best = k;
            }
            sc[tid] = best;
            __syncthreads();
            for (int off = 128; off >= 1; off >>= 1) {
                if (tid < off && sc[tid + off] > sc[tid]) sc[tid] = sc[tid + off];
                __syncthreads();
            }
            if (tid == 0) selk[s] = sc[0];
            __syncthreads();
            prev = selk[s];
        }
    }

    if (tid < 8) {
        unsigned long long k = selk[tid];
        unsigned uv = (unsigned)(k >> 32);
        unsigned bits = (uv & 0x80000000u) ? (uv ^ 0x80000000u) : ~uv;
        out_val[(size_t)bid * 8 + tid] = __uint_as_float(bits);
        int gi = 16383 - (int)(k & 0xFFFFFFFFull);
        out_idx[(size_t)bid * 8 + tid] = (float)gi;
    }
    if (tid < 32) {                      // 32 distinct indices -> ascending by rank
        int mine = 16383 - (int)(selk[tid] & 0xFFFFFFFFull);
        int rank = 0;
#pragma unroll
        for (int j = 0; j < 32; ++j) {
            int oj = 16383 - (int)(selk[j] & 0xFFFFFFFFull);
            rank += (oj < mine) ? 1 : 0;
        }
        idx_sorted[(size_t)bid * 32 + rank] = mine;
    }
}

// ---------------- kernel 3: LDS-tiled blockify [B,D,T,64,64] -> [B, T*1024, 4, D] ----------------
template <int D, int T>
__global__ __launch_bounds__(256) void blockify_tiled(const float* __restrict__ in,
                                                      float* __restrict__ out) {
    constexpr int NCH = D / 64;
    int wg = blockIdx.x;
    int ch = wg % NCH;
    int hb = (wg / NCH) % 32;
    int t  = (wg / (NCH * 32)) % T;
    int b  = wg / (NCH * 32 * T);
    int c0 = ch * 64;
    int tid = threadIdx.x;

    __shared__ float tile[64][129];

    {
        int x = tid & 63;
        int rw = tid >> 6;
#pragma unroll 8
        for (int i = 0; i < 32; ++i) {
            int r = i * 4 + rw;
            int c = r >> 1, si = r & 1;
            tile[c][si * 64 + x] =
                in[((((size_t)b * D + c0 + c) * T + t) * 64 + (2 * hb + si)) * 64 + x];
        }
    }
    __syncthreads();

    {
        int p = tid >> 6;
        int cc = tid & 63;
        int si = p >> 1, sj = p & 1;
        size_t nbase = (((size_t)b * T + t) * 1024 + (size_t)hb * 32);
#pragma unroll 8
        for (int wb = 0; wb < 32; ++wb) {
            out[(nbase + wb) * 4 * D + (size_t)p * D + c0 + cc] =
                tile[cc][si * 64 + 2 * wb + sj];
        }
    }
}

// ---------------- kernel 4: gathered block attention ----------------
__global__ __launch_bounds__(256) void attn_kernel(const float* __restrict__ m_in_b,
                                                   const float* __restrict__ m_out_b,
                                                   const float* __restrict__ q_b,
                                                   const int* __restrict__ idx_sorted,
                                                   float* __restrict__ out) {
    int bid = blockIdx.x;
    int b = bid >> 10, qblk = bid & 1023;
    int hb = qblk >> 5, wb = qblk & 31;
    int tid = threadIdx.x;
    int w = tid >> 6, lane = tid & 63;

    __shared__ float K[64][129];
    __shared__ float Q[4][128];
    __shared__ float P[4][128];
    __shared__ int   blks[32];

    if (tid < 32) blks[tid] = idx_sorted[(size_t)bid * 32 + tid];
    {
        const float* qsrc = q_b + (size_t)bid * 512;
        ((float*)Q)[tid]       = qsrc[tid];
        ((float*)Q)[tid + 256] = qsrc[tid + 256];
    }
    __syncthreads();

    const float scale = 0.08838834764831845f;
    float s01[2];
#pragma unroll 1
    for (int half = 0; half < 2; ++half) {
        if (half) __syncthreads();
#pragma unroll 4
        for (int ki = 0; ki < 16; ++ki) {
            int blk = blks[half * 16 + ki];
            const float* src = m_in_b + ((size_t)b * 16384 + blk) * 512;
            int p0 = tid >> 7, c0 = tid & 127;
            K[ki * 4 + p0][c0]     = src[tid];
            K[ki * 4 + p0 + 2][c0] = src[tid + 256];
        }
        __syncthreads();
        float acc = 0.f;
#pragma unroll 4
        for (int c = 0; c < 128; ++c) acc += K[lane][c] * Q[w][c];
        s01[half] = acc * scale;
    }

    float m = fmaxf(s01[0], s01[1]);
#pragma unroll
    for (int off = 32; off >= 1; off >>= 1) m = fmaxf(m, __shfl_xor(m, off, 64));
    float e0 = expf(s01[0] - m), e1 = expf(s01[1] - m);
    float sum = e0 + e1;
#pragma unroll
    for (int off = 32; off >= 1; off >>= 1) sum += __shfl_xor(sum, off, 64);
    float inv = 1.0f / sum;
    P[w][lane]      = e0 * inv;
    P[w][lane + 64] = e1 * inv;
    __syncthreads();

    float a0 = 0.f, a1 = 0.f, a2 = 0.f, a3 = 0.f;
    int d = tid;
#pragma unroll 1
    for (int ki = 0; ki < 32; ++ki) {
        const float* vsrc = m_out_b + ((size_t)b * 16384 + blks[ki]) * 1024;
#pragma unroll
        for (int p = 0; p < 4; ++p) {
            float vv = vsrc[p * 256 + d];
            int n = ki * 4 + p;
            a0 += P[0][n] * vv; a1 += P[1][n] * vv;
            a2 += P[2][n] * vv; a3 += P[3][n] * vv;
        }
    }
    size_t base = (((size_t)b * 256 + d) * 64 + hb * 2) * 64 + wb * 2;
    out[base]      = a0;
    out[base + 1]  = a1;
    out[base + 64] = a2;
    out[base + 65] = a3;
}

extern "C" void kernel_launch(void* const* d_in, const int* in_sizes, int n_in,
                              void* d_out, int out_size, void* d_ws, size_t ws_size,
                              hipStream_t stream) {
    const float* m_in  = (const float*)d_in[0];
    const float* m_out = (const float*)d_in[1];
    const float* q_in  = (const float*)d_in[2];
    const float* qk    = (const float*)d_in[3];

    char* ws = (char*)d_ws;
    float* m_out_b = (float*)(ws);                 // written after topk chain completes
    float* m_in_b  = (float*)(ws + 134217728);
    float* q_b     = (float*)(ws + 201326592);
    int*   idxs    = (int*)  (ws + 205520896);

    // transient top-k scratch inside the (not-yet-written) m_out_b region
    unsigned long long* cand = (unsigned long long*)(ws);        // 4MB
    float*    Mx  = (float*)   (ws + 4194304);                   // 512KB
    unsigned* t_u = (unsigned*)(ws + 4718592);                   // 8KB
    int*      cnt = (int*)     (ws + 4726784);                   // 8KB

    float* out     = (float*)d_out;
    float* out_mem = out;
    float* out_idx = out + 2097152;
    float* out_val = out + 2113536;

    qk_chunk_max<<<512, 256, 0, stream>>>(qk, Mx);
    qk_thresh   <<<512, 256, 0, stream>>>(Mx, t_u, cnt);
    qk_filter   <<<512, 256, 0, stream>>>(qk, t_u, cnt, cand);
    topk_select <<<2048, 256, 0, stream>>>(cand, cnt, qk, out_idx, out_val, idxs);

    blockify_tiled<128, 16><<<2 * 16 * 32 * 2, 256, 0, stream>>>(m_in, m_in_b);
    blockify_tiled<128, 1><<<2 * 1 * 32 * 2, 256, 0, stream>>>(q_in, q_b);
    blockify_tiled<256, 16><<<2 * 16 * 32 * 4, 256, 0, stream>>>(m_out, m_out_b);
    attn_kernel<<<2048, 256, 0, stream>>>(m_in_b, m_out_b, q_b, idxs, out_mem);
}